// Round 9
// baseline (356.747 us; speedup 1.0000x reference)
//
#include <hip/hip_runtime.h>

#define NB      1024
#define NWORLD  2048
#define DDIM    64
#define NWMAT   512
#define LISTCAP 32
#define CONV_BLOCKS 1088      // (512*64*64 + 2048*64) / (256*8)
#define GRID_MAIN   6144      // 4096 matched slots + 2048 fill, interleaved bid%3
#define STASH_ROW   512
#define STASH_ROWS  9
#define REPEAT      4         // MEASUREMENT ROUND: inflate main2 into top-5 counters

// stash inside d_out (rows 512.. are provably always-zero: nullary[:,0] < 512)
#define STASH_BYTE  268435456ull
#define OFF_WBF     0ull            // 4 MiB  bf16 W
#define OFF_WORLDS  4194304ull      // 256 KiB bf16 worlds
#define OFF_MLIST   4456448ull      // 2 KiB   packed (cnt<<16|r)
#define OFF_BLIST   4458496ull      // 64 KiB  per-row W indices

typedef __attribute__((ext_vector_type(4))) float f32x4;
typedef __attribute__((ext_vector_type(8))) short bf16x8;

__device__ __forceinline__ unsigned short f2bf(float f) {
    union { float f; unsigned u; } v; v.f = f;
    unsigned u = v.u;
    u += 0x7fffu + ((u >> 16) & 1u);   // RNE
    return (unsigned short)(u >> 16);
}

// ---- kernel 1: fused {f32->bf16 convert into stash} + {match lists into stash} ----
__global__ __launch_bounds__(256)
void prep(const float* __restrict__ W, const float* __restrict__ worlds,
          const int* __restrict__ nullary,
          char* outb, int* counters /* ws: [0]=zcnt [1]=mcnt */, int* zlist /* ws */)
{
    unsigned short* Wbf      = (unsigned short*)(outb + STASH_BYTE + OFF_WBF);
    unsigned short* worldsbf = (unsigned short*)(outb + STASH_BYTE + OFF_WORLDS);
    int* mlist               = (int*)(outb + STASH_BYTE + OFF_MLIST);
    int* blist               = (int*)(outb + STASH_BYTE + OFF_BLIST);

    const int bid = blockIdx.x;
    if (bid < CONV_BLOCKS) {
        const int NWE = NWMAT * DDIM * DDIM;
        int i = (bid * 256 + threadIdx.x) * 8;
        const float* src; unsigned short* dst; int off;
        if (i < NWE) { src = W;      dst = Wbf;      off = i; }
        else         { src = worlds; dst = worldsbf; off = i - NWE; }
        f32x4 a = *reinterpret_cast<const f32x4*>(src + off);
        f32x4 b = *reinterpret_cast<const f32x4*>(src + off + 4);
        bf16x8 r;
        r[0] = (short)f2bf(a[0]); r[1] = (short)f2bf(a[1]);
        r[2] = (short)f2bf(a[2]); r[3] = (short)f2bf(a[3]);
        r[4] = (short)f2bf(b[0]); r[5] = (short)f2bf(b[1]);
        r[6] = (short)f2bf(b[2]); r[7] = (short)f2bf(b[3]);
        *reinterpret_cast<bf16x8*>(dst + off) = r;
        return;
    }
    const int r    = (bid - CONV_BLOCKS) * 4 + (threadIdx.x >> 6);
    const int lane = threadIdx.x & 63;
    int base = 0;
    for (int c = 0; c < NB / 64; ++c) {
        const int n = c * 64 + lane;
        const bool m = (nullary[2 * n] == r);
        const unsigned long long mask = __ballot(m);
        if (m && r < NWMAT) {
            const int pos = base + __popcll(mask & ((1ull << lane) - 1ull));
            if (pos < LISTCAP) blist[r * LISTCAP + pos] = nullary[2 * n + 1];
        }
        base += __popcll(mask);
    }
    if (lane == 0) {
        const int cnt = (base > LISTCAP ? LISTCAP : base);
        if (cnt == 0 || r >= NWMAT) {
            if (r < STASH_ROW || r >= STASH_ROW + STASH_ROWS) {
                int p = atomicAdd(&counters[0], 1); zlist[p] = r;
            }
        } else {
            int p = atomicAdd(&counters[1], 1); mlist[p] = r | (cnt << 16);
        }
    }
}

// ---- kernel 2: R6 structure, body repeated REPEAT x (idempotent) for profiling ----
__global__ __launch_bounds__(256)
void main2(char* outb, int* counters, const int* __restrict__ zlist)
{
    const unsigned short* Wbf      = (const unsigned short*)(outb + STASH_BYTE + OFF_WBF);
    const unsigned short* worldsbf = (const unsigned short*)(outb + STASH_BYTE + OFF_WORLDS);
    const int* mlist               = (const int*)(outb + STASH_BYTE + OFF_MLIST);
    const int* blist               = (const int*)(outb + STASH_BYTE + OFF_BLIST);
    float* out                     = (float*)outb;

    const int bid = blockIdx.x;
    const int tid = threadIdx.x;

    if (bid % 3 == 2) {
        const int fid = bid / 3;
        const int total = counters[0] * 16;
        const f32x4 z = {0.f, 0.f, 0.f, 0.f};
        for (int rep = 0; rep < REPEAT; ++rep)
            for (int chunk = fid; chunk < total; chunk += 2048) {
                const int r = zlist[chunk >> 4];
                f32x4* o = reinterpret_cast<f32x4*>(out + (size_t)r * DDIM * NWORLD
                                                    + (size_t)(chunk & 15) * 8192) + tid;
                #pragma unroll
                for (int j = 0; j < 8; ++j)
                    o[j * 256] = z;
            }
        return;
    }

    const int mat  = (bid / 3) * 2 + (bid % 3);
    const int ridx = mat >> 3;
    if (ridx >= counters[1]) return;
    const int packed = mlist[ridx];
    const int r   = packed & 0xFFFF;
    const int cnt = packed >> 16;

    const int wave = tid >> 6, lane = tid & 63;
    const int col  = lane & 15, krow = lane >> 4;
    const int drow = tid >> 5;
    const int wl   = (tid & 31) * 4;

    __shared__ float T[DDIM][132];
    __shared__ int s_b[LISTCAP];
    if (tid < cnt) s_b[tid] = blist[r * LISTCAP + tid];
    __syncthreads();

    const int wtA = (mat & 7) * 2;

    for (int rep = 0; rep < REPEAT; ++rep) {
        bf16x8 bfrag[2][2][2];
        #pragma unroll
        for (int t = 0; t < 2; ++t)
            #pragma unroll
            for (int sub = 0; sub < 2; ++sub) {
                const int w0 = (wtA + t) * 128 + wave * 32 + sub * 16 + col;
                const unsigned short* wp = worldsbf + (size_t)w0 * DDIM + krow * 8;
                bfrag[t][sub][0] = *reinterpret_cast<const bf16x8*>(wp);
                bfrag[t][sub][1] = *reinterpret_cast<const bf16x8*>(wp + 32);
            }

        f32x4 acc[2][2][4];
        #pragma unroll
        for (int t = 0; t < 2; ++t)
            #pragma unroll
            for (int q = 0; q < 2; ++q)
                #pragma unroll
                for (int m = 0; m < 4; ++m)
                    acc[t][q][m] = (f32x4){0.f, 0.f, 0.f, 0.f};

        for (int mi = 0; mi < cnt; ++mi) {
            const unsigned short* Wb = Wbf + (size_t)s_b[mi] * DDIM * DDIM;
            bf16x8 afrag[4][2];
            #pragma unroll
            for (int mt = 0; mt < 4; ++mt) {
                const unsigned short* ap = Wb + (size_t)(mt * 16 + col) * DDIM + krow * 8;
                afrag[mt][0] = *reinterpret_cast<const bf16x8*>(ap);
                afrag[mt][1] = *reinterpret_cast<const bf16x8*>(ap + 32);
            }
            #pragma unroll
            for (int t = 0; t < 2; ++t)
                #pragma unroll
                for (int sub = 0; sub < 2; ++sub) {
                    f32x4 x[4];
                    #pragma unroll
                    for (int mt = 0; mt < 4; ++mt) {
                        f32x4 c = {0.f, 0.f, 0.f, 0.f};
                        c = __builtin_amdgcn_mfma_f32_16x16x32_bf16(afrag[mt][0], bfrag[t][sub][0], c, 0, 0, 0);
                        c = __builtin_amdgcn_mfma_f32_16x16x32_bf16(afrag[mt][1], bfrag[t][sub][1], c, 0, 0, 0);
                        x[mt] = c;
                    }
                    float p = 0.f;
                    #pragma unroll
                    for (int mt = 0; mt < 4; ++mt)
                        #pragma unroll
                        for (int j = 0; j < 4; ++j)
                            p += x[mt][j] * x[mt][j];
                    p += __shfl_xor(p, 16, 64);
                    p += __shfl_xor(p, 32, 64);
                    const float s = rsqrtf(fmaxf(p, 1e-12f));
                    #pragma unroll
                    for (int mt = 0; mt < 4; ++mt)
                        #pragma unroll
                        for (int j = 0; j < 4; ++j)
                            acc[t][sub][mt][j] += x[mt][j] * s;
                }
        }

        float* orow = out + (size_t)r * DDIM * NWORLD;
        #pragma unroll
        for (int t = 0; t < 2; ++t) {
            __syncthreads();
            #pragma unroll
            for (int sub = 0; sub < 2; ++sub)
                #pragma unroll
                for (int mt = 0; mt < 4; ++mt)
                    #pragma unroll
                    for (int j = 0; j < 4; ++j)
                        T[mt * 16 + krow * 4 + j][wave * 32 + sub * 16 + col] = acc[t][sub][mt][j];
            __syncthreads();

            float* obase = orow + (wtA + t) * 128;
            #pragma unroll
            for (int rd = 0; rd < 8; ++rd) {
                const int d = rd * 8 + drow;
                const f32x4 v = *reinterpret_cast<const f32x4*>(&T[d][wl]);
                *reinterpret_cast<f32x4*>(obase + (size_t)d * NWORLD + wl) = v;
            }
        }
    }
}

// ---- kernel 3: zero the stash rows (512..520) ----
__global__ __launch_bounds__(256)
void tail_zero(char* outb)
{
    f32x4* o = reinterpret_cast<f32x4*>(outb + STASH_BYTE);
    const f32x4 z = {0.f, 0.f, 0.f, 0.f};
    const int total = STASH_ROWS * DDIM * NWORLD / 4;
    for (int i = blockIdx.x * 256 + threadIdx.x; i < total; i += 288 * 256)
        o[i] = z;
}

extern "C" void kernel_launch(void* const* d_in, const int* in_sizes, int n_in,
                              void* d_out, int out_size, void* d_ws, size_t ws_size,
                              hipStream_t stream) {
    const float* worlds  = (const float*)d_in[0];
    const float* W       = (const float*)d_in[1];
    const int*   nullary = (const int*)d_in[2];
    char*        outb    = (char*)d_out;

    int* counters = (int*)d_ws;          // [0]=zcnt [1]=mcnt
    int* zlist    = counters + 4;

    hipMemsetAsync(counters, 0, 16, stream);
    prep<<<CONV_BLOCKS + NB / 4, 256, 0, stream>>>(W, worlds, nullary, outb, counters, zlist);
    main2<<<GRID_MAIN, 256, 0, stream>>>(outb, counters, zlist);
    tail_zero<<<288, 256, 0, stream>>>(outb);
}

// Round 10
// 118.728 us; speedup vs baseline: 3.0048x; 3.0048x over previous
//
#include <hip/hip_runtime.h>

#define NB      1024
#define NWORLD  2048
#define DDIM    64
#define NWMAT   512
#define CONV_BLOCKS 1088      // (512*64*64 + 2048*64) / (256*8)
#define LIST_BLOCKS 128       // 512 rows / 4 waves
#define GRID_MAIN   6144      // 4096 slot blocks + 2048 fill blocks, bid%3 interleave
#define STASH_ROW   512
#define STASH_ROWS  9
#define FILL_ROW0   (STASH_ROW + STASH_ROWS)          // 521
#define FILL_CHUNKS ((NB - FILL_ROW0) * 16)           // 503 rows x 16 chunks = 8048

// stash inside d_out (rows 512.. are provably always-zero: nullary[:,0] < 512)
#define STASH_BYTE  268435456ull
#define OFF_WBF     0ull            // 4 MiB  bf16 W
#define OFF_WORLDS  4194304ull      // 256 KiB bf16 worlds
#define OFF_DESC    4456448ull      // 64 KiB: 512 rows x 128B {cnt, b0..b30}

typedef __attribute__((ext_vector_type(4))) float f32x4;
typedef __attribute__((ext_vector_type(8))) short bf16x8;

__device__ __forceinline__ unsigned short f2bf(float f) {
    union { float f; unsigned u; } v; v.f = f;
    unsigned u = v.u;
    u += 0x7fffu + ((u >> 16) & 1u);   // RNE
    return (unsigned short)(u >> 16);
}

// ---- kernel 1: {f32->bf16 convert into stash} + {static desc table} ----
// No atomics, no workspace: fully deterministic static addressing.
__global__ __launch_bounds__(256)
void prep(const float* __restrict__ W, const float* __restrict__ worlds,
          const int* __restrict__ nullary, char* outb)
{
    unsigned short* Wbf      = (unsigned short*)(outb + STASH_BYTE + OFF_WBF);
    unsigned short* worldsbf = (unsigned short*)(outb + STASH_BYTE + OFF_WORLDS);
    int* descI               = (int*)(outb + STASH_BYTE + OFF_DESC);

    const int bid = blockIdx.x;
    if (bid < CONV_BLOCKS) {
        const int NWE = NWMAT * DDIM * DDIM;
        int i = (bid * 256 + threadIdx.x) * 8;
        const float* src; unsigned short* dst; int off;
        if (i < NWE) { src = W;      dst = Wbf;      off = i; }
        else         { src = worlds; dst = worldsbf; off = i - NWE; }
        f32x4 a = *reinterpret_cast<const f32x4*>(src + off);
        f32x4 b = *reinterpret_cast<const f32x4*>(src + off + 4);
        bf16x8 r;
        r[0] = (short)f2bf(a[0]); r[1] = (short)f2bf(a[1]);
        r[2] = (short)f2bf(a[2]); r[3] = (short)f2bf(a[3]);
        r[4] = (short)f2bf(b[0]); r[5] = (short)f2bf(b[1]);
        r[6] = (short)f2bf(b[2]); r[7] = (short)f2bf(b[3]);
        *reinterpret_cast<bf16x8*>(dst + off) = r;
        return;
    }
    // one wave per row r in [0,512): single-pass scan, index-ordered b list
    const int r    = (bid - CONV_BLOCKS) * 4 + (threadIdx.x >> 6);
    const int lane = threadIdx.x & 63;
    int base = 0;
    for (int c = 0; c < NB / 64; ++c) {
        const int n = c * 64 + lane;
        const bool m = (nullary[2 * n] == r);
        const unsigned long long mask = __ballot(m);
        if (m) {
            const int pos = base + __popcll(mask & ((1ull << lane) - 1ull));
            if (pos < 31) descI[r * 32 + 1 + pos] = nullary[2 * n + 1];
        }
        base += __popcll(mask);
    }
    if (lane == 0) descI[r * 32] = (base > 31 ? 31 : base);   // cnt (0 included)
}

// ---- kernel 2: static slot blocks + static fill blocks, bid%3 interleaved ----
__global__ __launch_bounds__(256)
void main2(char* outb)
{
    const unsigned short* Wbf      = (const unsigned short*)(outb + STASH_BYTE + OFF_WBF);
    const unsigned short* worldsbf = (const unsigned short*)(outb + STASH_BYTE + OFF_WORLDS);
    const int4* desc4              = (const int4*)(outb + STASH_BYTE + OFF_DESC);
    const int*  descI              = (const int*)desc4;
    float* out                     = (float*)outb;

    const int bid = blockIdx.x;
    const int tid = threadIdx.x;
    const f32x4 z = {0.f, 0.f, 0.f, 0.f};

    if (bid % 3 == 2) {
        // ---- pure fill role: rows 521..1023, fully static, zero loads ----
        const int fid = bid / 3;                 // 0..2047
        for (int chunk = fid; chunk < FILL_CHUNKS; chunk += 2048) {
            const int r = FILL_ROW0 + (chunk >> 4);
            f32x4* o = reinterpret_cast<f32x4*>(out + (size_t)r * DDIM * NWORLD
                                                + (size_t)(chunk & 15) * 8192) + tid;
            #pragma unroll
            for (int j = 0; j < 8; ++j)
                o[j * 256] = z;
        }
        return;
    }

    // ---- slot role: slot -> (row, tile pair) statically ----
    const int slot = (bid / 3) * 2 + (bid % 3);  // 0..4095
    const int r    = slot >> 3;                  // 0..511
    const int wtA  = (slot & 7) * 2;             // tiles wtA, wtA+1

    const int wave = tid >> 6, lane = tid & 63;
    const int col  = lane & 15, krow = lane >> 4;
    const int drow = tid >> 5;
    const int wl   = (tid & 31) * 4;

    // issue B-fragment loads FIRST (static addresses, independent of desc)
    bf16x8 bfrag[2][2][2];
    #pragma unroll
    for (int t = 0; t < 2; ++t)
        #pragma unroll
        for (int sub = 0; sub < 2; ++sub) {
            const int w0 = (wtA + t) * 128 + wave * 32 + sub * 16 + col;
            const unsigned short* wp = worldsbf + (size_t)w0 * DDIM + krow * 8;
            bfrag[t][sub][0] = *reinterpret_cast<const bf16x8*>(wp);
            bfrag[t][sub][1] = *reinterpret_cast<const bf16x8*>(wp + 32);
        }

    // entire preamble chain = this one 16B load
    const int4 h = desc4[r * 8];                 // {cnt, b0, b1, b2}
    const int cnt = h.x;
    float* orow = out + (size_t)r * DDIM * NWORLD;

    if (cnt == 0) {
        // unmatched row < 512: zero-fill this slot's two tiles (256 cols x 64 d)
        float* obase = orow + wtA * 128;
        #pragma unroll
        for (int k = 0; k < 16; ++k) {
            const int idx = k * 256 + tid;
            const int d  = idx >> 6;
            const int c4 = (idx & 63) * 4;
            *reinterpret_cast<f32x4*>(obase + (size_t)d * NWORLD + c4) = z;
        }
        return;
    }

    __shared__ float T[DDIM][132];

    f32x4 acc[2][2][4];
    #pragma unroll
    for (int t = 0; t < 2; ++t)
        #pragma unroll
        for (int q = 0; q < 2; ++q)
            #pragma unroll
            for (int m = 0; m < 4; ++m)
                acc[t][q][m] = z;

    for (int mi = 0; mi < cnt; ++mi) {
        int b;
        if      (mi == 0) b = h.y;
        else if (mi == 1) b = h.z;
        else if (mi == 2) b = h.w;
        else              b = descI[r * 32 + 1 + mi];   // block-uniform scalar load
        const unsigned short* Wb = Wbf + (size_t)b * DDIM * DDIM;
        bf16x8 afrag[4][2];
        #pragma unroll
        for (int mt = 0; mt < 4; ++mt) {
            const unsigned short* ap = Wb + (size_t)(mt * 16 + col) * DDIM + krow * 8;
            afrag[mt][0] = *reinterpret_cast<const bf16x8*>(ap);
            afrag[mt][1] = *reinterpret_cast<const bf16x8*>(ap + 32);
        }
        #pragma unroll
        for (int t = 0; t < 2; ++t)
            #pragma unroll
            for (int sub = 0; sub < 2; ++sub) {
                f32x4 x[4];
                #pragma unroll
                for (int mt = 0; mt < 4; ++mt) {
                    f32x4 c = z;
                    c = __builtin_amdgcn_mfma_f32_16x16x32_bf16(afrag[mt][0], bfrag[t][sub][0], c, 0, 0, 0);
                    c = __builtin_amdgcn_mfma_f32_16x16x32_bf16(afrag[mt][1], bfrag[t][sub][1], c, 0, 0, 0);
                    x[mt] = c;
                }
                float p = 0.f;
                #pragma unroll
                for (int mt = 0; mt < 4; ++mt)
                    #pragma unroll
                    for (int j = 0; j < 4; ++j)
                        p += x[mt][j] * x[mt][j];
                p += __shfl_xor(p, 16, 64);
                p += __shfl_xor(p, 32, 64);
                const float s = rsqrtf(fmaxf(p, 1e-12f));
                #pragma unroll
                for (int mt = 0; mt < 4; ++mt)
                    #pragma unroll
                    for (int j = 0; j < 4; ++j)
                        acc[t][sub][mt][j] += x[mt][j] * s;
            }
    }

    // LDS transpose + stores, per tile
    #pragma unroll
    for (int t = 0; t < 2; ++t) {
        __syncthreads();   // WAR on T
        #pragma unroll
        for (int sub = 0; sub < 2; ++sub)
            #pragma unroll
            for (int mt = 0; mt < 4; ++mt)
                #pragma unroll
                for (int j = 0; j < 4; ++j)
                    T[mt * 16 + krow * 4 + j][wave * 32 + sub * 16 + col] = acc[t][sub][mt][j];
        __syncthreads();

        float* obase = orow + (wtA + t) * 128;
        #pragma unroll
        for (int rd = 0; rd < 8; ++rd) {
            const int d = rd * 8 + drow;
            const f32x4 v = *reinterpret_cast<const f32x4*>(&T[d][wl]);
            *reinterpret_cast<f32x4*>(obase + (size_t)d * NWORLD + wl) = v;
        }
    }
}

// ---- kernel 3: zero the stash rows (512..520) ----
__global__ __launch_bounds__(256)
void tail_zero(char* outb)
{
    f32x4* o = reinterpret_cast<f32x4*>(outb + STASH_BYTE);
    const f32x4 z = {0.f, 0.f, 0.f, 0.f};
    const int total = STASH_ROWS * DDIM * NWORLD / 4;
    for (int i = blockIdx.x * 256 + threadIdx.x; i < total; i += 288 * 256)
        o[i] = z;
}

extern "C" void kernel_launch(void* const* d_in, const int* in_sizes, int n_in,
                              void* d_out, int out_size, void* d_ws, size_t ws_size,
                              hipStream_t stream) {
    const float* worlds  = (const float*)d_in[0];
    const float* W       = (const float*)d_in[1];
    const int*   nullary = (const int*)d_in[2];
    char*        outb    = (char*)d_out;

    prep<<<CONV_BLOCKS + LIST_BLOCKS, 256, 0, stream>>>(W, worlds, nullary, outb);
    main2<<<GRID_MAIN, 256, 0, stream>>>(outb);
    tail_zero<<<288, 256, 0, stream>>>(outb);
}